// Round 1
// baseline (127.348 us; speedup 1.0000x reference)
//
#include <hip/hip_runtime.h>

// Problem constants (B=8, C=64, H=128, W=256)
#define HW_ 32768          // H*W
#define OUTHALF 16777216ULL
#define SMEM_BYTES 117760

typedef short short8  __attribute__((ext_vector_type(8)));
typedef short short4v __attribute__((ext_vector_type(4)));
typedef float f32x4   __attribute__((ext_vector_type(4)));

__device__ __forceinline__ unsigned short f2bf(float f) {
  unsigned u = __builtin_bit_cast(unsigned, f);
  u += 0x7fffu + ((u >> 16) & 1u);          // RNE; inputs are finite
  return (unsigned short)(u >> 16);
}
__device__ __forceinline__ float bf2f(short s) {
  unsigned u = ((unsigned)(unsigned short)s) << 16;
  return __builtin_bit_cast(float, u);
}
__device__ __forceinline__ char* swz(char* base, int row, int colByte) {
  // arrays with 128-byte rows; XOR-swizzle kills stride-128 bank conflicts
  return base + row * 128 + (colByte ^ ((row & 7) << 4));
}
__device__ __forceinline__ f32x4 zero4() { f32x4 z = {0.f, 0.f, 0.f, 0.f}; return z; }

// ---------------- setup: M̂[x][y] = sum_o Wq'[o][x] Wk'[o][y], u[y] = sum_o bq''[o] Wk'[o][y]
__global__ void pam_setup(const float* __restrict__ Wq, const float* __restrict__ bq,
                          const float* __restrict__ gq, const float* __restrict__ betaq,
                          const float* __restrict__ mq, const float* __restrict__ vq,
                          const float* __restrict__ Wk, const float* __restrict__ gk,
                          const float* __restrict__ vk,
                          short* __restrict__ Mb, float* __restrict__ u) {
  int blk = blockIdx.x, tid = threadIdx.x;
  if (blk < 16) {
    int entry = blk * 256 + tid;
    int x = entry >> 6, y = entry & 63;
    float acc = 0.f;
    for (int o = 0; o < 64; ++o) {
      float sq = gq[o] * rsqrtf(vq[o] + 1e-5f);
      float sk = gk[o] * rsqrtf(vk[o] + 1e-5f);
      acc += Wq[o * 64 + x] * sq * Wk[o * 64 + y] * sk;
    }
    Mb[x * 64 + y] = (short)f2bf(acc);
  } else if (tid < 64) {
    int y = tid;
    float acc = 0.f;
    for (int o = 0; o < 64; ++o) {
      float sq = gq[o] * rsqrtf(vq[o] + 1e-5f);
      float sk = gk[o] * rsqrtf(vk[o] + 1e-5f);
      float bqq = bq[o] * sq + betaq[o] - mq[o] * sq;
      acc += bqq * Wk[o * 64 + y] * sk;
    }
    u[y] = acc;
  }
}

// ---------------- main: one block per (b,h)
__global__ __launch_bounds__(512, 2) void pam_main(
    const float* __restrict__ fl, const float* __restrict__ fr,
    const short* __restrict__ Mb, const float* __restrict__ uvec,
    float* __restrict__ out) {
  extern __shared__ __align__(16) char sm[];
  char* XLt = sm;                 // [256][64] bf16, pos-major (chan contiguous)
  char* XRt = sm + 32768;
  char* Kt  = sm + 65536;         // [64][64] bf16: conv'd key tile
  char* Xn  = sm + 73728;         // [64 c][64 v] bf16: V tile
  char* Pt  = sm + 81920;         // 8 waves x [32 w][64 v] bf16
  float* tl = (float*)(sm + 114688); // [2][256] t/64
  float* Db = (float*)(sm + 116736); // [8][32] 1/D

  const int tid  = threadIdx.x;
  const int lane = tid & 63;
  const int wave = tid >> 6;
  const int l15  = lane & 15;
  const int g    = lane >> 4;
  const int bb   = blockIdx.x >> 7;
  const int hh   = blockIdx.x & 127;
  const int rowOff = hh * 256;
  const int base_b = bb * 64;

  // ---- stage XLt / XRt (f32 global -> bf16 LDS, transposed) ----
  for (int it = 0; it < 16; ++it) {
    int unit = it * 512 + tid;          // 0..8191
    int tensor = unit >> 12;            // 0: left, 1: right
    int rem = unit & 4095;
    int cq = rem >> 8;                  // channel quad 0..15
    int p  = rem & 255;                 // position
    const float* src = tensor ? fr : fl;
    char* dst = tensor ? XRt : XLt;
    int gbase = (base_b + cq * 4) * HW_ + rowOff + p;
    float v0 = src[gbase];
    float v1 = src[gbase + HW_];
    float v2 = src[gbase + 2 * HW_];
    float v3 = src[gbase + 3 * HW_];
    short4v pk;
    pk[0] = (short)f2bf(v0); pk[1] = (short)f2bf(v1);
    pk[2] = (short)f2bf(v2); pk[3] = (short)f2bf(v3);
    *(short4v*)swz(dst, p, cq * 8) = pk;
  }
  __syncthreads();

  // ---- t[v]/64 = (u . X_kv[:,v]) / 64 ----
  {
    int sel = tid >> 8;                 // 0: from XRt (attend1), 1: from XLt (attend2)
    int p   = tid & 255;
    char* xt = sel ? XLt : XRt;
    float acc = 0.f;
    #pragma unroll
    for (int j = 0; j < 8; ++j) {
      short8 xv = *(const short8*)swz(xt, p, j * 16);
      #pragma unroll
      for (int e = 0; e < 8; ++e)
        acc = fmaf(bf2f(xv[e]), uvec[j * 8 + e], acc);
    }
    tl[sel * 256 + p] = acc * 0.015625f;
  }

  const short8* mbv = (const short8*)Mb;

  for (int at = 0; at < 2; ++at) {
    char* Xq  = at ? XRt : XLt;         // query-side (B of S-GEMM)
    char* Xkv = at ? XLt : XRt;         // key/value-side (A of conv)
    const float* skv = at ? fl : fr;    // V source in global
    const float* tp  = tl + at * 256;
    float* outp = out + (at ? OUTHALF : 0) + (size_t)base_b * HW_ + rowOff;

    f32x4 acc_o[2][4];
    #pragma unroll
    for (int i = 0; i < 2; ++i)
      #pragma unroll
      for (int j = 0; j < 4; ++j) acc_o[i][j] = zero4();
    float dacc0 = 0.f, dacc1 = 0.f;
    const int w0 = wave * 32;

    for (int vt = 0; vt < 4; ++vt) {
      __syncthreads();                  // prev tile's reads done
      // ---- phase A: stage V tile (f32 -> bf16) ----
      {
        int c  = tid >> 3;
        int v8 = (tid & 7) * 8;
        const float* s = skv + (base_b + c) * HW_ + rowOff + vt * 64 + v8;
        f32x4 A0 = *(const f32x4*)s;
        f32x4 A1 = *(const f32x4*)(s + 4);
        short8 pk;
        pk[0] = (short)f2bf(A0[0]); pk[1] = (short)f2bf(A0[1]);
        pk[2] = (short)f2bf(A0[2]); pk[3] = (short)f2bf(A0[3]);
        pk[4] = (short)f2bf(A1[0]); pk[5] = (short)f2bf(A1[1]);
        pk[6] = (short)f2bf(A1[2]); pk[7] = (short)f2bf(A1[3]);
        *(short8*)swz(Xn, c, v8 * 2) = pk;
      }
      // ---- phase A: conv tile K̃[vl][e] = sum_d Xkv[vl][d] * M̂[e][d] ----
      #pragma unroll
      for (int s2 = 0; s2 < 2; ++s2) {
        int sidx = wave * 2 + s2;       // 16 subtiles over 8 waves
        int mi = sidx >> 2, nj = sidx & 3;
        f32x4 accc = zero4();
        #pragma unroll
        for (int kk = 0; kk < 2; ++kk) {
          short8 af = *(const short8*)swz(Xkv, vt * 64 + mi * 16 + l15, (kk * 32 + 8 * g) * 2);
          short8 bf = mbv[(nj * 16 + l15) * 8 + kk * 4 + g];
          accc = __builtin_amdgcn_mfma_f32_16x16x32_bf16(af, bf, accc, 0, 0, 0);
        }
        int e2 = (nj * 16 + l15) * 2;
        #pragma unroll
        for (int r = 0; r < 4; ++r)
          *(short*)swz(Kt, mi * 16 + 4 * g + r, e2) = (short)f2bf(accc[r]);
      }
      __syncthreads();                  // K̃ and V tile visible

      // ---- phase B: S-GEMM  S_T[vl][w] = sum_e K̃[vl][e] Xq[w][e] ----
      short8 bqf[2][2];
      #pragma unroll
      for (int nj = 0; nj < 2; ++nj)
        #pragma unroll
        for (int kk = 0; kk < 2; ++kk)
          bqf[nj][kk] = *(const short8*)swz(Xq, w0 + nj * 16 + l15, (kk * 32 + 8 * g) * 2);

      f32x4 accs[4][2];
      #pragma unroll
      for (int mi = 0; mi < 4; ++mi) {
        accs[mi][0] = zero4(); accs[mi][1] = zero4();
        #pragma unroll
        for (int kk = 0; kk < 2; ++kk) {
          short8 af = *(const short8*)swz(Kt, mi * 16 + l15, (kk * 32 + 8 * g) * 2);
          accs[mi][0] = __builtin_amdgcn_mfma_f32_16x16x32_bf16(af, bqf[0][kk], accs[mi][0], 0, 0, 0);
          accs[mi][1] = __builtin_amdgcn_mfma_f32_16x16x32_bf16(af, bqf[1][kk], accs[mi][1], 0, 0, 0);
        }
      }
      // ---- exp + P̃ -> LDS (per-wave) + D accumulation ----
      #pragma unroll
      for (int mi = 0; mi < 4; ++mi) {
        f32x4 tr = *(const f32x4*)(tp + vt * 64 + mi * 16 + 4 * g);
        #pragma unroll
        for (int nj = 0; nj < 2; ++nj) {
          f32x4 pv;
          #pragma unroll
          for (int r = 0; r < 4; ++r)
            pv[r] = __expf(fmaf(accs[mi][nj][r], 0.015625f, tr[r]));
          if (nj == 0) dacc0 += pv[0] + pv[1] + pv[2] + pv[3];
          else         dacc1 += pv[0] + pv[1] + pv[2] + pv[3];
          short4v p4;
          p4[0] = (short)f2bf(pv[0]); p4[1] = (short)f2bf(pv[1]);
          p4[2] = (short)f2bf(pv[2]); p4[3] = (short)f2bf(pv[3]);
          *(short4v*)swz(Pt, wave * 32 + nj * 16 + l15, mi * 32 + 8 * g) = p4;
        }
      }
      // ---- PV-GEMM: O_T[w][c] += sum_v P̃[w][v] V[c][v] ----
      #pragma unroll
      for (int kk = 0; kk < 2; ++kk) {
        short8 pa0 = *(const short8*)swz(Pt, wave * 32 + l15,      (kk * 32 + 8 * g) * 2);
        short8 pa1 = *(const short8*)swz(Pt, wave * 32 + 16 + l15, (kk * 32 + 8 * g) * 2);
        #pragma unroll
        for (int nj2 = 0; nj2 < 4; ++nj2) {
          short8 xb = *(const short8*)swz(Xn, nj2 * 16 + l15, (kk * 32 + 8 * g) * 2);
          acc_o[0][nj2] = __builtin_amdgcn_mfma_f32_16x16x32_bf16(pa0, xb, acc_o[0][nj2], 0, 0, 0);
          acc_o[1][nj2] = __builtin_amdgcn_mfma_f32_16x16x32_bf16(pa1, xb, acc_o[1][nj2], 0, 0, 0);
        }
      }
    } // vt

    // ---- D reduce (rows were split across lane groups) + epilogue ----
    dacc0 += __shfl_xor(dacc0, 16); dacc0 += __shfl_xor(dacc0, 32);
    dacc1 += __shfl_xor(dacc1, 16); dacc1 += __shfl_xor(dacc1, 32);
    if (lane < 16) {
      Db[wave * 32 + lane]      = __builtin_amdgcn_rcpf(dacc0);
      Db[wave * 32 + 16 + lane] = __builtin_amdgcn_rcpf(dacc1);
    }
    #pragma unroll
    for (int mi2 = 0; mi2 < 2; ++mi2) {
      f32x4 rd = *(const f32x4*)(Db + wave * 32 + mi2 * 16 + 4 * g);
      #pragma unroll
      for (int nj2 = 0; nj2 < 4; ++nj2) {
        int c = nj2 * 16 + l15;
        f32x4 v;
        v[0] = acc_o[mi2][nj2][0] * rd[0];
        v[1] = acc_o[mi2][nj2][1] * rd[1];
        v[2] = acc_o[mi2][nj2][2] * rd[2];
        v[3] = acc_o[mi2][nj2][3] * rd[3];
        *(f32x4*)(outp + (size_t)c * HW_ + w0 + mi2 * 16 + 4 * g) = v;
      }
    }
  } // at
}

extern "C" void kernel_launch(void* const* d_in, const int* in_sizes, int n_in,
                              void* d_out, int out_size, void* d_ws, size_t ws_size,
                              hipStream_t stream) {
  (void)in_sizes; (void)n_in; (void)out_size; (void)ws_size;
  const float* fl    = (const float*)d_in[0];
  const float* fr    = (const float*)d_in[1];
  const float* Wq    = (const float*)d_in[2];
  const float* bq    = (const float*)d_in[3];
  const float* gq    = (const float*)d_in[4];
  const float* betaq = (const float*)d_in[5];
  const float* mq    = (const float*)d_in[6];
  const float* vq    = (const float*)d_in[7];
  const float* Wk    = (const float*)d_in[8];
  const float* gk    = (const float*)d_in[10];
  const float* vk    = (const float*)d_in[13];
  short* Mb = (short*)d_ws;
  float* u  = (float*)((char*)d_ws + 8192);
  float* out = (float*)d_out;

  hipFuncSetAttribute((const void*)pam_main,
                      hipFuncAttributeMaxDynamicSharedMemorySize, SMEM_BYTES);
  pam_setup<<<17, 256, 0, stream>>>(Wq, bq, gq, betaq, mq, vq, Wk, gk, vk, Mb, u);
  pam_main<<<1024, 512, SMEM_BYTES, stream>>>(fl, fr, Mb, u, out);
}